// Round 2
// baseline (415.698 us; speedup 1.0000x reference)
//
#include <hip/hip_runtime.h>
#include <cfloat>

// Problem constants (from reference setup_inputs): B=4096, C=10, H=W=30
#define CC     10
#define HWP    900
#define NBATCH 4096
#define NPIX_INV (1.0/3686400.0)   // 1/(B*H*W)

// Workspace: facc[0]=sum(ce*w), facc[1]=sum((changed-t_changed)^2)
//            iacc[0]=count(exact), iacc[1]=count(copy), iacc[2]=sum(missing)
__global__ __launch_bounds__(256, 4) void per_sample_kernel(
    const float* __restrict__ pred,
    const float* __restrict__ target,
    const float* __restrict__ grid,
    float* __restrict__ facc,
    unsigned int* __restrict__ iacc)
{
    const int b   = blockIdx.x;
    const int tid = threadIdx.x;
    const size_t base = (size_t)b * (CC * HWP);

    float ce_w_sum = 0.f;
    // packed counts: bits [0:10)=pred!=target, [10:20)=target!=grid, [20:30)=pred!=grid
    unsigned cnts = 0;
    // packed presence masks: bits [0:10)=pred colors, [16:26)=target colors
    unsigned masks = 0;

    if (tid < 225) {                 // 225 groups of 4 pixels = 900 (16B-aligned)
        const int hw = tid * 4;
        // online-logsumexp state per pixel k: m=running max(pred), s=running sum,
        // pat=pred at target-argmax, tmax/gmax, packed argmax indices
        float m[4], s[4], pat[4], tmax[4], gmax[4];
        int   pidx[4], tidx[4], gidx[4];
        #pragma unroll
        for (int k = 0; k < 4; ++k) {
            m[k] = -FLT_MAX; s[k] = 0.f; pat[k] = 0.f;
            tmax[k] = -FLT_MAX; gmax[k] = -FLT_MAX;
            pidx[k] = 0; tidx[k] = 0; gidx[k] = 0;
        }
        #pragma unroll
        for (int c = 0; c < CC; ++c) {
            const float4 pv = *(const float4*)(pred   + base + c * HWP + hw);
            const float4 tv = *(const float4*)(target + base + c * HWP + hw);
            const float4 gv = *(const float4*)(grid   + base + c * HWP + hw);
            const float pa[4] = {pv.x, pv.y, pv.z, pv.w};
            const float ta[4] = {tv.x, tv.y, tv.z, tv.w};
            const float ga[4] = {gv.x, gv.y, gv.z, gv.w};
            #pragma unroll
            for (int k = 0; k < 4; ++k) {
                // online logsumexp + pred argmax
                const float nm = fmaxf(m[k], pa[k]);
                s[k] = s[k] * __expf(m[k] - nm) + __expf(pa[k] - nm);
                if (pa[k] > m[k]) pidx[k] = c;
                m[k] = nm;
                // target argmax (+ gather pred at that index)
                if (ta[k] > tmax[k]) { tmax[k] = ta[k]; tidx[k] = c; pat[k] = pa[k]; }
                // input argmax
                if (ga[k] > gmax[k]) { gmax[k] = ga[k]; gidx[k] = c; }
            }
        }
        #pragma unroll
        for (int k = 0; k < 4; ++k) {
            const float ce  = m[k] + __logf(s[k]) - pat[k];   // lse - pred[tidx]
            const unsigned inc = (pidx[k] != tidx[k]);
            ce_w_sum += ce * (1.f + 2.f * (float)inc);
            cnts  += inc
                   + ((unsigned)(tidx[k] != gidx[k]) << 10)
                   + ((unsigned)(pidx[k] != gidx[k]) << 20);
            masks |= (1u << pidx[k]) | (1u << (16 + tidx[k]));
        }
    }

    // wave-64 shuffle reduction (3 values)
    #pragma unroll
    for (int off = 32; off > 0; off >>= 1) {
        ce_w_sum += __shfl_down(ce_w_sum, off);
        cnts     += __shfl_down(cnts, off);
        masks    |= __shfl_down(masks, off);
    }

    __shared__ float    s_ce[4];
    __shared__ unsigned s_cn[4], s_mk[4];
    const int wave = tid >> 6, lane = tid & 63;
    if (lane == 0) { s_ce[wave] = ce_w_sum; s_cn[wave] = cnts; s_mk[wave] = masks; }
    __syncthreads();
    if (tid == 0) {
        float ce = 0.f; unsigned cn = 0, mk = 0;
        #pragma unroll
        for (int w = 0; w < 4; ++w) { ce += s_ce[w]; cn += s_cn[w]; mk |= s_mk[w]; }
        const int pt = cn & 0x3FF, tg = (cn >> 10) & 0x3FF, pg = (cn >> 20) & 0x3FF;
        atomicAdd(&facc[0], ce);
        const float d = (float)(pg - tg) * (1.0f / 900.0f);
        atomicAdd(&facc[1], d * d);
        if (pt == 0)           atomicAdd(&iacc[0], 1u);      // exact match
        if (tg > 0 && pg == 0) atomicAdd(&iacc[1], 1u);      // should_not_copy & did_copy
        const unsigned miss = (mk >> 16) & ~mk & 0x3FFu;
        if (miss)              atomicAdd(&iacc[2], (unsigned)__popc(miss));
    }
}

__global__ void finalize_kernel(const float* __restrict__ facc,
                                const unsigned* __restrict__ iacc,
                                float* __restrict__ out)
{
    if (threadIdx.x == 0 && blockIdx.x == 0) {
        const float ce_mean        = (float)((double)facc[0] * NPIX_INV);
        const float ce_loss        = ce_mean + 0.5f * (float)iacc[2];
        const float exact_bonus    = -10.0f * ((float)iacc[0] / (float)NBATCH);
        const float copy_penalty   =   5.0f * ((float)iacc[1] / (float)NBATCH);
        const float transform_diff = (facc[1] / (float)NBATCH) * 2.0f;
        out[0] = ce_loss + exact_bonus + copy_penalty + transform_diff;
        out[1] = ce_loss;
        out[2] = exact_bonus;
        out[3] = copy_penalty;
        out[4] = transform_diff;
        out[5] = (float)iacc[0];   // jnp.sum(exact)
    }
}

extern "C" void kernel_launch(void* const* d_in, const int* in_sizes, int n_in,
                              void* d_out, int out_size, void* d_ws, size_t ws_size,
                              hipStream_t stream) {
    const float* pred   = (const float*)d_in[0];
    const float* target = (const float*)d_in[1];
    const float* grid   = (const float*)d_in[2];
    float*    out  = (float*)d_out;
    float*    facc = (float*)d_ws;
    unsigned* iacc = (unsigned*)((char*)d_ws + 16);

    hipMemsetAsync(d_ws, 0, 64, stream);
    per_sample_kernel<<<NBATCH, 256, 0, stream>>>(pred, target, grid, facc, iacc);
    finalize_kernel<<<1, 64, 0, stream>>>(facc, iacc, out);
}

// Round 3
// 405.452 us; speedup vs baseline: 1.0253x; 1.0253x over previous
//
#include <hip/hip_runtime.h>
#include <cfloat>

// Problem constants (from reference setup_inputs): B=4096, C=10, H=W=30
#define CC     10
#define HWP    900
#define NBATCH 4096
#define NPIX_INV (1.0/3686400.0)   // 1/(B*H*W)

// Workspace: facc[0]=sum(ce*w), facc[1]=sum((changed-t_changed)^2)
//            iacc[0]=count(exact), iacc[1]=count(copy), iacc[2]=sum(missing)
//
// MLP strategy: all 30 float4 loads issued up-front (30 KB in flight per wave),
// consumed afterwards from registers. launch_bounds(256,3) -> ~168 VGPR cap so
// the allocator doesn't squeeze to 36 regs (R1/R2 showed 36 regs => ~2 loads in
// flight => latency-bound at 162 us).
__global__ __launch_bounds__(256, 3) void per_sample_kernel(
    const float* __restrict__ pred,
    const float* __restrict__ target,
    const float* __restrict__ grid,
    float* __restrict__ facc,
    unsigned int* __restrict__ iacc)
{
    const int b   = blockIdx.x;
    const int tid = threadIdx.x;
    const size_t base = (size_t)b * (CC * HWP);

    float ce_w_sum = 0.f;
    // packed counts: bits [0:10)=pred!=target, [10:20)=target!=grid, [20:30)=pred!=grid
    unsigned cnts = 0;
    // packed presence masks: bits [0:10)=pred colors, [16:26)=target colors
    unsigned masks = 0;

    if (tid < 225) {                 // 225 groups of 4 pixels = 900 (16B-aligned)
        const int hw = tid * 4;
        const float* pb = pred   + base + hw;
        const float* tb = target + base + hw;
        const float* gb = grid   + base + hw;

        // ---- issue ALL loads first (maximize memory-level parallelism) ----
        float4 pv[CC], tv[CC], gv[CC];
        #pragma unroll
        for (int c = 0; c < CC; ++c) pv[c] = *(const float4*)(pb + c * HWP);
        #pragma unroll
        for (int c = 0; c < CC; ++c) tv[c] = *(const float4*)(tb + c * HWP);
        #pragma unroll
        for (int c = 0; c < CC; ++c) gv[c] = *(const float4*)(gb + c * HWP);

        // ---- consume from registers (all indices static under full unroll) ----
        float pmax[4], tmax[4], gmax[4], pat[4], esum[4];
        int   pidx[4], tidx[4], gidx[4];
        #pragma unroll
        for (int k = 0; k < 4; ++k) {
            pmax[k] = -FLT_MAX; tmax[k] = -FLT_MAX; gmax[k] = -FLT_MAX;
            pidx[k] = 0; tidx[k] = 0; gidx[k] = 0; pat[k] = 0.f; esum[k] = 0.f;
        }
        // pred argmax
        #pragma unroll
        for (int c = 0; c < CC; ++c) {
            const float pa[4] = {pv[c].x, pv[c].y, pv[c].z, pv[c].w};
            #pragma unroll
            for (int k = 0; k < 4; ++k)
                if (pa[k] > pmax[k]) { pmax[k] = pa[k]; pidx[k] = c; }
        }
        // target argmax + gather pred at target-argmax (static index c)
        #pragma unroll
        for (int c = 0; c < CC; ++c) {
            const float ta[4] = {tv[c].x, tv[c].y, tv[c].z, tv[c].w};
            const float pa[4] = {pv[c].x, pv[c].y, pv[c].z, pv[c].w};
            #pragma unroll
            for (int k = 0; k < 4; ++k)
                if (ta[k] > tmax[k]) { tmax[k] = ta[k]; tidx[k] = c; pat[k] = pa[k]; }
        }
        // exp-sum with known max (10 exps/pixel, no serial rescale chain)
        #pragma unroll
        for (int c = 0; c < CC; ++c) {
            const float pa[4] = {pv[c].x, pv[c].y, pv[c].z, pv[c].w};
            #pragma unroll
            for (int k = 0; k < 4; ++k)
                esum[k] += __expf(pa[k] - pmax[k]);
        }
        // input_grid argmax
        #pragma unroll
        for (int c = 0; c < CC; ++c) {
            const float ga[4] = {gv[c].x, gv[c].y, gv[c].z, gv[c].w};
            #pragma unroll
            for (int k = 0; k < 4; ++k)
                if (ga[k] > gmax[k]) { gmax[k] = ga[k]; gidx[k] = c; }
        }
        // per-pixel terms
        #pragma unroll
        for (int k = 0; k < 4; ++k) {
            const float ce  = pmax[k] + __logf(esum[k]) - pat[k];   // lse - pred[tidx]
            const unsigned inc = (pidx[k] != tidx[k]);
            ce_w_sum += ce * (1.f + 2.f * (float)inc);
            cnts  += inc
                   + ((unsigned)(tidx[k] != gidx[k]) << 10)
                   + ((unsigned)(pidx[k] != gidx[k]) << 20);
            masks |= (1u << pidx[k]) | (1u << (16 + tidx[k]));
        }
    }

    // wave-64 shuffle reduction (3 values)
    #pragma unroll
    for (int off = 32; off > 0; off >>= 1) {
        ce_w_sum += __shfl_down(ce_w_sum, off);
        cnts     += __shfl_down(cnts, off);
        masks    |= __shfl_down(masks, off);
    }

    __shared__ float    s_ce[4];
    __shared__ unsigned s_cn[4], s_mk[4];
    const int wave = tid >> 6, lane = tid & 63;
    if (lane == 0) { s_ce[wave] = ce_w_sum; s_cn[wave] = cnts; s_mk[wave] = masks; }
    __syncthreads();
    if (tid == 0) {
        float ce = 0.f; unsigned cn = 0, mk = 0;
        #pragma unroll
        for (int w = 0; w < 4; ++w) { ce += s_ce[w]; cn += s_cn[w]; mk |= s_mk[w]; }
        const int pt = cn & 0x3FF, tg = (cn >> 10) & 0x3FF, pg = (cn >> 20) & 0x3FF;
        atomicAdd(&facc[0], ce);
        const float d = (float)(pg - tg) * (1.0f / 900.0f);
        atomicAdd(&facc[1], d * d);
        if (pt == 0)           atomicAdd(&iacc[0], 1u);      // exact match
        if (tg > 0 && pg == 0) atomicAdd(&iacc[1], 1u);      // should_not_copy & did_copy
        const unsigned miss = (mk >> 16) & ~mk & 0x3FFu;
        if (miss)              atomicAdd(&iacc[2], (unsigned)__popc(miss));
    }
}

__global__ void finalize_kernel(const float* __restrict__ facc,
                                const unsigned* __restrict__ iacc,
                                float* __restrict__ out)
{
    if (threadIdx.x == 0 && blockIdx.x == 0) {
        const float ce_mean        = (float)((double)facc[0] * NPIX_INV);
        const float ce_loss        = ce_mean + 0.5f * (float)iacc[2];
        const float exact_bonus    = -10.0f * ((float)iacc[0] / (float)NBATCH);
        const float copy_penalty   =   5.0f * ((float)iacc[1] / (float)NBATCH);
        const float transform_diff = (facc[1] / (float)NBATCH) * 2.0f;
        out[0] = ce_loss + exact_bonus + copy_penalty + transform_diff;
        out[1] = ce_loss;
        out[2] = exact_bonus;
        out[3] = copy_penalty;
        out[4] = transform_diff;
        out[5] = (float)iacc[0];   // jnp.sum(exact)
    }
}

extern "C" void kernel_launch(void* const* d_in, const int* in_sizes, int n_in,
                              void* d_out, int out_size, void* d_ws, size_t ws_size,
                              hipStream_t stream) {
    const float* pred   = (const float*)d_in[0];
    const float* target = (const float*)d_in[1];
    const float* grid   = (const float*)d_in[2];
    float*    out  = (float*)d_out;
    float*    facc = (float*)d_ws;
    unsigned* iacc = (unsigned*)((char*)d_ws + 16);

    hipMemsetAsync(d_ws, 0, 64, stream);
    per_sample_kernel<<<NBATCH, 256, 0, stream>>>(pred, target, grid, facc, iacc);
    finalize_kernel<<<1, 64, 0, stream>>>(facc, iacc, out);
}